// Round 7
// baseline (1312.245 us; speedup 1.0000x reference)
//
#include <hip/hip_runtime.h>
#include <hip/hip_bf16.h>

// DGCNN-style KNN classifier. B=8, N=2048, K=10.
// Runtime dtype probe: g_flag=1 -> bf16 inputs, 0 -> fp32. Output same dtype.
// Scratch in static __device__ globals; every byte read is written earlier in
// the same launch (graph-replay safe).
//
// R6->R7: dist64/w5max were LDS-BW-bound fp32 tile GEMMs (VALUBusy 63%,
// MfmaUtil 0, 2.5e7 bank conflicts). Replaced with MFMA 16x16x32_bf16 using
// split-bf16 (hi+lo, 3 products; dropped lo*lo term ~2^-18 rel err). Row-major
// [row][k] fragments for BOTH operands (X.X^T / cat.W5^T) -> no LDS staging.

#define NEG 0.2f
#define FMAX 3.402823466e+38f

typedef __hip_bfloat16 bf16;
typedef __attribute__((ext_vector_type(8))) short s8v;    // 8 bf16
typedef __attribute__((ext_vector_type(4))) float f32x4;  // MFMA acc

#define BB 8
#define NN 2048
#define BNTOT (BB * NN)

#define OFF_CAT ((size_t)0)
#define OFF_G (OFF_CAT + (size_t)BNTOT * 512)
#define OFF_NORMS (OFF_G + (size_t)BNTOT * 128)
#define OFF_PART (OFF_NORMS + BNTOT)
#define OFF_POOLED (OFF_PART + 8 * 1024 * 32)
#define OFF_H1 (OFF_POOLED + 8 * 1024)
#define OFF_H2 (OFF_H1 + 8 * 512)
#define WSF_TOTAL (OFF_H2 + 8 * 256)

__device__ float g_ws_f[WSF_TOTAL];          // ~43.1 MB
__device__ float g_D[(size_t)BNTOT * NN];    // 134 MB distance matrix
__device__ int g_ws_i[(size_t)BNTOT * 10];   // knn idx
__device__ int g_flag;                       // 1 = bf16 inputs, 0 = fp32
__device__ unsigned short g_hi[(size_t)BNTOT * 512];   // split-bf16 hi (X side)
__device__ unsigned short g_lo[(size_t)BNTOT * 512];   // split-bf16 lo
__device__ unsigned short g_whi[1024 * 512];           // split W5 hi
__device__ unsigned short g_wlo[1024 * 512];           // split W5 lo

__device__ __forceinline__ float ldany(const void* p, size_t i, int isb) {
  if (isb) return __bfloat162float(((const bf16*)p)[i]);
  return ((const float*)p)[i];
}

// ---------------- dtype probe ----------------
__global__ void probe_kernel(const void* pts) {
  const unsigned* w = (const unsigned*)pts;
  int cnt = 0;
  for (int i = 0; i < 256; ++i) {
    unsigned e2 = (w[i] >> 7) & 0xFF;
    cnt += (e2 >= 110 && e2 <= 135);
  }
  g_flag = (cnt > 128) ? 1 : 0;
}

// ---------------- norms ----------------
template <bool XDYN>
__global__ void norms_kernel(const void* xraw, size_t xoff, int lda, int C, int BN) {
  const int isb = g_flag;
  float* norms = g_ws_f + OFF_NORMS;
  int row = blockIdx.x * (blockDim.x >> 6) + (threadIdx.x >> 6);
  int lane = threadIdx.x & 63;
  if (row >= BN) return;
  float s = 0.f;
  for (int c = lane; c < C; c += 64) {
    float v = XDYN ? ldany(xraw, (size_t)row * lda + c, isb)
                   : g_ws_f[xoff + (size_t)row * lda + c];
    s += v * v;
  }
#pragma unroll
  for (int off = 32; off > 0; off >>= 1) s += __shfl_down(s, off, 64);
  if (lane == 0) norms[row] = s;
}

// ---------------- split-bf16: x -> hi + lo (row-major, K padded) ----------------
// dst 0 -> g_hi/g_lo ; dst 1 -> g_whi/g_wlo. Cpad power of 2, cshift=log2(Cpad).
__global__ void split_kernel(const void* xraw, size_t xoff, int lda, int C,
                             int cshift, int dst, int total) {
  int i = blockIdx.x * blockDim.x + threadIdx.x;
  if (i >= total) return;
  const int isb = g_flag;
  int cpadm1 = (1 << cshift) - 1;
  int r = i >> cshift, c = i & cpadm1;
  float v = 0.f;
  if (c < C)
    v = xraw ? ldany(xraw, (size_t)r * lda + c, isb) : g_ws_f[xoff + (size_t)r * lda + c];
  bf16 h = __float2bfloat16(v);
  float hf = __bfloat162float(h);
  bf16 l = __float2bfloat16(v - hf);
  unsigned short* H = dst ? g_whi : g_hi;
  unsigned short* L = dst ? g_wlo : g_lo;
  H[i] = *(unsigned short*)&h;
  L[i] = *(unsigned short*)&l;
}

// ---------------- MFMA distance: D[b][q][m] = |m|^2 - 2 q.m ----------------
// block 256 thr = 4 waves; block tile 64q x 64m; wave: 16q x 64m.
template <int CPAD>
__global__ __launch_bounds__(256) void dist_mfma(int N) {
  const int tid = threadIdx.x;
  const int wave = tid >> 6, lane = tid & 63;
  const int quad = lane >> 4, l16 = lane & 15;
  const int b = blockIdx.z;
  const int q0 = blockIdx.y * 64, m0 = blockIdx.x * 64;
  const size_t rowb = (size_t)b * N;
  f32x4 acc[4];
#pragma unroll
  for (int s = 0; s < 4; ++s) acc[s] = (f32x4){0.f, 0.f, 0.f, 0.f};

  const unsigned short* H = g_hi;
  const unsigned short* L = g_lo;
  const size_t abase = (rowb + q0 + wave * 16 + l16) * CPAD + quad * 8;
#pragma unroll
  for (int k0 = 0; k0 < CPAD; k0 += 32) {
    s8v ah = *(const s8v*)(H + abase + k0);
    s8v al = *(const s8v*)(L + abase + k0);
#pragma unroll
    for (int s = 0; s < 4; ++s) {
      size_t bbase = (rowb + m0 + s * 16 + l16) * CPAD + quad * 8 + k0;
      s8v bh = *(const s8v*)(H + bbase);
      s8v bl = *(const s8v*)(L + bbase);
      acc[s] = __builtin_amdgcn_mfma_f32_16x16x32_bf16(ah, bh, acc[s], 0, 0, 0);
      acc[s] = __builtin_amdgcn_mfma_f32_16x16x32_bf16(ah, bl, acc[s], 0, 0, 0);
      acc[s] = __builtin_amdgcn_mfma_f32_16x16x32_bf16(al, bh, acc[s], 0, 0, 0);
    }
  }
  const float* norms = g_ws_f + OFF_NORMS;
#pragma unroll
  for (int s = 0; s < 4; ++s) {
    int m = m0 + s * 16 + l16;
    float nm = norms[rowb + m];
#pragma unroll
    for (int r = 0; r < 4; ++r) {
      int q = q0 + wave * 16 + quad * 4 + r;  // C/D: col=lane&15, row=quad*4+reg
      g_D[(rowb + q) * N + m] = nm - 2.f * acc[s][r];
    }
  }
}

// ---------------- top-10: one wave per row ----------------
__global__ __launch_bounds__(256) void topk_kernel(int N) {
  int wid = (blockIdx.x * blockDim.x + threadIdx.x) >> 6;
  int lane = threadIdx.x & 63;
  if (wid >= BNTOT) return;
  int q = wid & (N - 1);
  const float* drow = g_D + (size_t)wid * N;
  float dv[32];
  const int base = lane * 32;
#pragma unroll
  for (int j = 0; j < 32; j += 4) {
    float4 d4 = *(const float4*)(drow + base + j);
    dv[j] = d4.x; dv[j + 1] = d4.y; dv[j + 2] = d4.z; dv[j + 3] = d4.w;
  }
  if (q >= base && q < base + 32) dv[q - base] = FMAX;
  int* ob = g_ws_i + (size_t)wid * 10;
  for (int k = 0; k < 10; ++k) {
    float bd = dv[0]; int bj = 0;
#pragma unroll
    for (int j = 1; j < 32; ++j)
      if (dv[j] < bd) { bd = dv[j]; bj = j; }
    float rd = bd; int rm = base + bj;
#pragma unroll
    for (int off = 32; off > 0; off >>= 1) {
      float od = __shfl_down(rd, off, 64);
      int om = __shfl_down(rm, off, 64);
      if (od < rd || (od == rd && om < rm)) { rd = od; rm = om; }
    }
    rm = __shfl(rm, 0, 64);
    if (lane == 0) ob[k] = rm;
    if (rm >= base && rm < base + 32) dv[rm - base] = FMAX;
  }
}

// ---------------- G[z][BN][64] = X @ W_half[o_base:+64]^T ----------------
template <bool XDYN, int C>
__global__ __launch_bounds__(256) void gmat64_kernel(const void* xraw, size_t xoff,
                                                     int lda, const void* W,
                                                     int o_base, int BN) {
  const int isb = g_flag;
  constexpr int CC = (C <= 4) ? 4 : 64;
  constexpr int NCH = (C + CC - 1) / CC;
  __shared__ __align__(16) float at[CC][68];
  __shared__ __align__(16) float wt[CC][68];
  const int tid = threadIdx.x;
  const int ty = tid >> 4, tx = tid & 15;
  const int r0 = blockIdx.x * 64;
  const int z = blockIdx.z;
  float* Gz = g_ws_f + OFF_G + (size_t)z * BN * 64;
  float acc[4][4];
#pragma unroll
  for (int i = 0; i < 4; ++i)
#pragma unroll
    for (int j = 0; j < 4; ++j) acc[i][j] = 0.f;

  for (int ch = 0; ch < NCH; ++ch) {
    int c0 = ch * CC;
    for (int i = tid; i < 64 * CC; i += 256) {
      int r = i / CC, c = i % CC; int cg = c0 + c;
      size_t gi = (size_t)(r0 + r) * lda + cg;
      at[c][r] = (cg < C) ? (XDYN ? ldany(xraw, gi, isb) : g_ws_f[xoff + gi]) : 0.f;
    }
    for (int i = tid; i < 64 * CC; i += 256) {
      int r = i / CC, c = i % CC; int cg = c0 + c;
      size_t wi = (size_t)(o_base + r) * (2 * C) + (size_t)z * C + cg;
      wt[c][r] = (cg < C) ? ldany(W, wi, isb) : 0.f;
    }
    __syncthreads();
#pragma unroll 8
    for (int c = 0; c < CC; ++c) {
      const float4 a4 = *(const float4*)&at[c][4 * ty];
      const float4 w4 = *(const float4*)&wt[c][4 * tx];
      acc[0][0] += a4.x * w4.x; acc[0][1] += a4.x * w4.y; acc[0][2] += a4.x * w4.z; acc[0][3] += a4.x * w4.w;
      acc[1][0] += a4.y * w4.x; acc[1][1] += a4.y * w4.y; acc[1][2] += a4.y * w4.z; acc[1][3] += a4.y * w4.w;
      acc[2][0] += a4.z * w4.x; acc[2][1] += a4.z * w4.y; acc[2][2] += a4.z * w4.z; acc[2][3] += a4.z * w4.w;
      acc[3][0] += a4.w * w4.x; acc[3][1] += a4.w * w4.y; acc[3][2] += a4.w * w4.z; acc[3][3] += a4.w * w4.w;
    }
    __syncthreads();
  }
#pragma unroll
  for (int i = 0; i < 4; ++i)
#pragma unroll
    for (int j = 0; j < 4; ++j)
      Gz[(size_t)(r0 + 4 * ty + i) * 64 + 4 * tx + j] = acc[i][j];
}

// ---------------- edge-conv epilogue (64-out chunk) ----------------
__global__ void edge_epi64(const void* s, const void* t, int coff,
                           size_t outoff, int BN, int N) {
  const int isb = g_flag;
  int tid = threadIdx.x;
  int p = tid >> 6, o = tid & 63;
  int row = blockIdx.x * 4 + p;
  const float* G1 = g_ws_f + OFF_G;
  const float* G2 = G1 + (size_t)BN * 64;
  float* out = g_ws_f + outoff;
  int b = row / N;
  const int* id = g_ws_i + (size_t)row * 10;
  float g1n = G1[(size_t)row * 64 + o];
  float base = G2[(size_t)row * 64 + o] - g1n;
  float sv = ldany(s, coff + o, isb), tv = ldany(t, coff + o, isb);
  float mx = -FMAX;
#pragma unroll
  for (int k = 0; k < 10; ++k) {
    int m = id[k];
    m = (m < 0) ? 0 : ((m >= N) ? N - 1 : m);
    float h = sv * (G1[((size_t)b * N + m) * 64 + o] + base) + tv;
    h = (h >= 0.f) ? h : NEG * h;
    mx = fmaxf(mx, h);
  }
  out[(size_t)row * 512 + o] = mx;
}

// ---------------- W5 MFMA + max over n (s5>0 so scale/bias/lrelu after max) ----
__global__ __launch_bounds__(256) void w5max_mfma(const void* s5, const void* t5, int N) {
  const int tid = threadIdx.x;
  const int wave = tid >> 6, lane = tid & 63;
  const int quad = lane >> 4, l16 = lane & 15;
  const int b = blockIdx.z;
  const int o0 = blockIdx.y * 64, n0 = blockIdx.x * 64;
  f32x4 acc[4];
#pragma unroll
  for (int s = 0; s < 4; ++s) acc[s] = (f32x4){0.f, 0.f, 0.f, 0.f};

  const size_t abase = ((size_t)b * N + n0 + wave * 16 + l16) * 512 + quad * 8;
#pragma unroll 4
  for (int k0 = 0; k0 < 512; k0 += 32) {
    s8v ah = *(const s8v*)(g_hi + abase + k0);
    s8v al = *(const s8v*)(g_lo + abase + k0);
#pragma unroll
    for (int s = 0; s < 4; ++s) {
      size_t bbase = (size_t)(o0 + s * 16 + l16) * 512 + quad * 8 + k0;
      s8v bh = *(const s8v*)(g_whi + bbase);
      s8v bl = *(const s8v*)(g_wlo + bbase);
      acc[s] = __builtin_amdgcn_mfma_f32_16x16x32_bf16(ah, bh, acc[s], 0, 0, 0);
      acc[s] = __builtin_amdgcn_mfma_f32_16x16x32_bf16(ah, bl, acc[s], 0, 0, 0);
      acc[s] = __builtin_amdgcn_mfma_f32_16x16x32_bf16(al, bh, acc[s], 0, 0, 0);
    }
  }
  __shared__ float red[4][64];
  const int isb = g_flag;
#pragma unroll
  for (int s = 0; s < 4; ++s) {
    float m4 = fmaxf(fmaxf(acc[s][0], acc[s][1]), fmaxf(acc[s][2], acc[s][3]));
#pragma unroll
    for (int off = 16; off < 64; off <<= 1) m4 = fmaxf(m4, __shfl_down(m4, off, 64));
    if (quad == 0) red[wave][s * 16 + l16] = m4;
  }
  __syncthreads();
  if (tid < 64) {
    float m = fmaxf(fmaxf(red[0][tid], red[1][tid]), fmaxf(red[2][tid], red[3][tid]));
    int o = o0 + tid;
    float sv = ldany(s5, o, isb), tv = ldany(t5, o, isb);
    float h = sv * m + tv;
    h = (h >= 0.f) ? h : NEG * h;
    g_ws_f[OFF_PART + ((size_t)b * 1024 + o) * 32 + blockIdx.x] = h;
  }
}

__global__ void poolred_kernel() {
  const float* part = g_ws_f + OFF_PART;
  float* pooled = g_ws_f + OFF_POOLED;
  int i = blockIdx.x * blockDim.x + threadIdx.x;
  if (i >= 8 * 1024) return;
  const float* p = part + (size_t)i * 32;
  float m = -FMAX;
#pragma unroll
  for (int j = 0; j < 32; ++j) m = fmaxf(m, p[j]);
  pooled[i] = m;
}

// ---------------- FC: one wave per output ----------------
__global__ void fc_kernel(size_t inoff, const void* W, const void* bias,
                          const void* s, const void* t, size_t outoff, int has_out,
                          void* OUTB, int Bb, int IC, int OC, int act) {
  const int isb = g_flag;
  const float* IN = g_ws_f + inoff;
  int gw = (blockIdx.x * blockDim.x + threadIdx.x) >> 6;
  int lane = threadIdx.x & 63;
  if (gw >= Bb * OC) return;
  int b = gw / OC, o = gw % OC;
  const float* in = IN + (size_t)b * IC;
  float acc = 0.f;
  for (int c = lane; c < IC; c += 64) acc += in[c] * ldany(W, (size_t)o * IC + c, isb);
#pragma unroll
  for (int off = 32; off > 0; off >>= 1) acc += __shfl_down(acc, off, 64);
  if (lane == 0) {
    float h = acc;
    if (bias) h += ldany(bias, o, isb);
    if (s) h = h * ldany(s, o, isb) + ldany(t, o, isb);
    if (act) h = (h >= 0.f) ? h : NEG * h;
    if (has_out) g_ws_f[outoff + (size_t)b * OC + o] = h;
    if (OUTB) {
      if (isb) ((bf16*)OUTB)[(size_t)b * OC + o] = __float2bfloat16(h);
      else ((float*)OUTB)[(size_t)b * OC + o] = h;
    }
  }
}

extern "C" void kernel_launch(void* const* d_in, const int* in_sizes, int n_in,
                              void* d_out, int out_size, void* d_ws, size_t ws_size,
                              hipStream_t stream) {
  const int B = 8, N = 2048, BN = B * N;
  const void* points = d_in[0];
  const void *W1 = d_in[1], *s1 = d_in[2], *t1 = d_in[3];
  const void *W2 = d_in[4], *s2 = d_in[5], *t2 = d_in[6];
  const void *W3 = d_in[7], *s3 = d_in[8], *t3 = d_in[9];
  const void *W4 = d_in[10], *s4 = d_in[11], *t4 = d_in[12];
  const void *W5 = d_in[13], *s5 = d_in[14], *t5 = d_in[15];
  const void *Wf1 = d_in[16], *sf1 = d_in[17], *tf1 = d_in[18];
  const void *Wf2 = d_in[19], *bf2 = d_in[20], *sf2 = d_in[21], *tf2 = d_in[22];
  const void *Wf3 = d_in[23], *bf3 = d_in[24];

  probe_kernel<<<1, 1, 0, stream>>>(points);
  // split W5 (1024 x 512) once
  split_kernel<<<(1024 * 512) / 256, 256, 0, stream>>>(W5, 0, 512, 512, 9, 1, 1024 * 512);

  // ---- layer 1: points (C=3, Cpad=32) -> cat[:, 0:64)
  norms_kernel<true><<<BN / 4, 256, 0, stream>>>(points, 0, 3, 3, BN);
  split_kernel<<<(BN * 32) / 256, 256, 0, stream>>>(points, 0, 3, 3, 5, 0, BN * 32);
  dist_mfma<32><<<dim3(N / 64, N / 64, B), 256, 0, stream>>>(N);
  topk_kernel<<<BN / 4, 256, 0, stream>>>(N);
  gmat64_kernel<true, 3><<<dim3(BN / 64, 1, 2), 256, 0, stream>>>(points, 0, 3, W1, 0, BN);
  edge_epi64<<<BN / 4, 256, 0, stream>>>(s1, t1, 0, OFF_CAT + 0, BN, N);
  // ---- layer 2: cat[:,0:64) (C=64) -> cat[:, 64:128)
  norms_kernel<false><<<BN / 4, 256, 0, stream>>>(nullptr, OFF_CAT + 0, 512, 64, BN);
  split_kernel<<<(BN * 64) / 256, 256, 0, stream>>>(nullptr, OFF_CAT + 0, 512, 64, 6, 0, BN * 64);
  dist_mfma<64><<<dim3(N / 64, N / 64, B), 256, 0, stream>>>(N);
  topk_kernel<<<BN / 4, 256, 0, stream>>>(N);
  gmat64_kernel<false, 64><<<dim3(BN / 64, 1, 2), 256, 0, stream>>>(nullptr, OFF_CAT + 0, 512, W2, 0, BN);
  edge_epi64<<<BN / 4, 256, 0, stream>>>(s2, t2, 0, OFF_CAT + 64, BN, N);
  // ---- layer 3: cat[:,64:128) (C=64) -> cat[:, 128:256)
  norms_kernel<false><<<BN / 4, 256, 0, stream>>>(nullptr, OFF_CAT + 64, 512, 64, BN);
  split_kernel<<<(BN * 64) / 256, 256, 0, stream>>>(nullptr, OFF_CAT + 64, 512, 64, 6, 0, BN * 64);
  dist_mfma<64><<<dim3(N / 64, N / 64, B), 256, 0, stream>>>(N);
  topk_kernel<<<BN / 4, 256, 0, stream>>>(N);
  for (int c = 0; c < 2; ++c) {
    gmat64_kernel<false, 64><<<dim3(BN / 64, 1, 2), 256, 0, stream>>>(nullptr, OFF_CAT + 64, 512, W3, c * 64, BN);
    edge_epi64<<<BN / 4, 256, 0, stream>>>(s3, t3, c * 64, OFF_CAT + 128 + c * 64, BN, N);
  }
  // ---- layer 4: cat[:,128:256) (C=128) -> cat[:, 256:512)
  norms_kernel<false><<<BN / 4, 256, 0, stream>>>(nullptr, OFF_CAT + 128, 512, 128, BN);
  split_kernel<<<(BN * 128) / 256, 256, 0, stream>>>(nullptr, OFF_CAT + 128, 512, 128, 7, 0, BN * 128);
  dist_mfma<128><<<dim3(N / 64, N / 64, B), 256, 0, stream>>>(N);
  topk_kernel<<<BN / 4, 256, 0, stream>>>(N);
  for (int c = 0; c < 4; ++c) {
    gmat64_kernel<false, 128><<<dim3(BN / 64, 1, 2), 256, 0, stream>>>(nullptr, OFF_CAT + 128, 512, W4, c * 64, BN);
    edge_epi64<<<BN / 4, 256, 0, stream>>>(s4, t4, c * 64, OFF_CAT + 256 + c * 64, BN, N);
  }
  // ---- W5 (split full cat, 512 cols) + global max pool
  split_kernel<<<(BN * 512) / 256, 256, 0, stream>>>(nullptr, OFF_CAT, 512, 512, 9, 0, BN * 512);
  w5max_mfma<<<dim3(32, 16, 8), 256, 0, stream>>>(s5, t5, N);
  poolred_kernel<<<32, 256, 0, stream>>>();
  // ---- FC head
  fc_kernel<<<(8 * 512 * 64) / 256, 256, 0, stream>>>(OFF_POOLED, Wf1, nullptr, sf1, tf1, OFF_H1, 1, nullptr, 8, 1024, 512, 1);
  fc_kernel<<<(8 * 256 * 64) / 256, 256, 0, stream>>>(OFF_H1, Wf2, bf2, sf2, tf2, OFF_H2, 1, nullptr, 8, 512, 256, 1);
  fc_kernel<<<6, 256, 0, stream>>>(OFF_H2, Wf3, bf3, nullptr, nullptr, 0, 0, d_out, 8, 256, 3, 0);
}

// Round 8
// 911.819 us; speedup vs baseline: 1.4392x; 1.4392x over previous
//
#include <hip/hip_runtime.h>
#include <hip/hip_bf16.h>

// DGCNN-style KNN classifier. B=8, N=2048, K=10.
// Runtime dtype probe: g_flag=1 -> bf16 inputs, 0 -> fp32. Output same dtype.
// Scratch in static __device__ globals; every byte read is written earlier in
// the same launch (graph-replay safe).
//
// R7->R8: MFMA kernels were address-generation bound (MfmaUtil 7%: per-lane
// 16B loads at 1KB row stride = 64 scattered segments/wave ~ 64cyc/load).
// Split arrays now stored in MFMA-fragment-tile order: tile t=(r/16)*(CPAD/32)
// + (k/32), interior lane-linear (quad*128 + l16*8 + j) -> every fragment load
// is one coalesced 1KB wave load.

#define NEG 0.2f
#define FMAX 3.402823466e+38f

typedef __hip_bfloat16 bf16;
typedef __attribute__((ext_vector_type(8))) short s8v;    // 8 bf16
typedef __attribute__((ext_vector_type(4))) float f32x4;  // MFMA acc

#define BB 8
#define NN 2048
#define BNTOT (BB * NN)

#define OFF_CAT ((size_t)0)
#define OFF_G (OFF_CAT + (size_t)BNTOT * 512)
#define OFF_NORMS (OFF_G + (size_t)BNTOT * 128)
#define OFF_PART (OFF_NORMS + BNTOT)
#define OFF_POOLED (OFF_PART + 8 * 1024 * 32)
#define OFF_H1 (OFF_POOLED + 8 * 1024)
#define OFF_H2 (OFF_H1 + 8 * 512)
#define WSF_TOTAL (OFF_H2 + 8 * 256)

__device__ float g_ws_f[WSF_TOTAL];          // ~43.1 MB
__device__ float g_D[(size_t)BNTOT * NN];    // 134 MB distance matrix
__device__ int g_ws_i[(size_t)BNTOT * 10];   // knn idx
__device__ int g_flag;                       // 1 = bf16 inputs, 0 = fp32
__device__ unsigned short g_hi[(size_t)BNTOT * 512];   // split-bf16 hi (frag-tiled)
__device__ unsigned short g_lo[(size_t)BNTOT * 512];
__device__ unsigned short g_whi[1024 * 512];           // split W5 (frag-tiled)
__device__ unsigned short g_wlo[1024 * 512];

__device__ __forceinline__ float ldany(const void* p, size_t i, int isb) {
  if (isb) return __bfloat162float(((const bf16*)p)[i]);
  return ((const float*)p)[i];
}

// ---------------- dtype probe ----------------
__global__ void probe_kernel(const void* pts) {
  const unsigned* w = (const unsigned*)pts;
  int cnt = 0;
  for (int i = 0; i < 256; ++i) {
    unsigned e2 = (w[i] >> 7) & 0xFF;
    cnt += (e2 >= 110 && e2 <= 135);
  }
  g_flag = (cnt > 128) ? 1 : 0;
}

// ---------------- norms ----------------
template <bool XDYN>
__global__ void norms_kernel(const void* xraw, size_t xoff, int lda, int C, int BN) {
  const int isb = g_flag;
  float* norms = g_ws_f + OFF_NORMS;
  int row = blockIdx.x * (blockDim.x >> 6) + (threadIdx.x >> 6);
  int lane = threadIdx.x & 63;
  if (row >= BN) return;
  float s = 0.f;
  for (int c = lane; c < C; c += 64) {
    float v = XDYN ? ldany(xraw, (size_t)row * lda + c, isb)
                   : g_ws_f[xoff + (size_t)row * lda + c];
    s += v * v;
  }
#pragma unroll
  for (int off = 32; off > 0; off >>= 1) s += __shfl_down(s, off, 64);
  if (lane == 0) norms[row] = s;
}

// ------- split-bf16 into MFMA-fragment-tile layout -------
// out[t*512 + quad*128 + l16*8 + j] where t=(r/16)*(CPAD/32)+(k/32),
// k = (k/32)*32 + quad*8 + j, r = (r/16)*16 + l16.
// Thread = output index -> coalesced writes. csh2 = log2(CPAD/32).
__global__ void split_kernel(const void* xraw, size_t xoff, int lda, int C,
                             int csh2, int dst, int total) {
  int i = blockIdx.x * blockDim.x + threadIdx.x;
  if (i >= total) return;
  const int isb = g_flag;
  int t = i >> 9, win = i & 511;
  int quad = win >> 7, l16 = (win >> 3) & 15, j = win & 7;
  int ktiles_m1 = (1 << csh2) - 1;
  int rg = t >> csh2, kt = t & ktiles_m1;
  int r = rg * 16 + l16;
  int c = kt * 32 + quad * 8 + j;
  float v = 0.f;
  if (c < C)
    v = xraw ? ldany(xraw, (size_t)r * lda + c, isb) : g_ws_f[xoff + (size_t)r * lda + c];
  bf16 h = __float2bfloat16(v);
  float hf = __bfloat162float(h);
  bf16 l = __float2bfloat16(v - hf);
  unsigned short* H = dst ? g_whi : g_hi;
  unsigned short* L = dst ? g_wlo : g_lo;
  H[i] = *(unsigned short*)&h;
  L[i] = *(unsigned short*)&l;
}

// ---------------- MFMA distance: D[b][q][m] = |m|^2 - 2 q.m ----------------
// block 256 thr = 4 waves; block tile 64q x 64m; wave: 16q x 64m.
template <int CPAD>
__global__ __launch_bounds__(256) void dist_mfma(int N) {
  constexpr int KT = CPAD >> 5;
  const int tid = threadIdx.x;
  const int wave = tid >> 6, lane = tid & 63;
  const int quad = lane >> 4, l16 = lane & 15;
  const int b = blockIdx.z;
  const int q0 = blockIdx.y * 64, m0 = blockIdx.x * 64;
  const size_t rowb = (size_t)b * N;
  f32x4 acc[4];
#pragma unroll
  for (int s = 0; s < 4; ++s) acc[s] = (f32x4){0.f, 0.f, 0.f, 0.f};

  const int arg = (int)((rowb + q0) >> 4) + wave;   // A row-group
  const int brg0 = (int)((rowb + m0) >> 4);         // B row-group base
#pragma unroll
  for (int kt = 0; kt < KT; ++kt) {
    const size_t abase = ((size_t)arg * KT + kt) * 512 + lane * 8;
    s8v ah = *(const s8v*)(g_hi + abase);
    s8v al = *(const s8v*)(g_lo + abase);
#pragma unroll
    for (int s = 0; s < 4; ++s) {
      const size_t bbase = ((size_t)(brg0 + s) * KT + kt) * 512 + lane * 8;
      s8v bh = *(const s8v*)(g_hi + bbase);
      s8v bl = *(const s8v*)(g_lo + bbase);
      acc[s] = __builtin_amdgcn_mfma_f32_16x16x32_bf16(ah, bh, acc[s], 0, 0, 0);
      acc[s] = __builtin_amdgcn_mfma_f32_16x16x32_bf16(ah, bl, acc[s], 0, 0, 0);
      acc[s] = __builtin_amdgcn_mfma_f32_16x16x32_bf16(al, bh, acc[s], 0, 0, 0);
    }
  }
  const float* norms = g_ws_f + OFF_NORMS;
#pragma unroll
  for (int s = 0; s < 4; ++s) {
    int m = m0 + s * 16 + l16;
    float nm = norms[rowb + m];
#pragma unroll
    for (int r = 0; r < 4; ++r) {
      int q = q0 + wave * 16 + quad * 4 + r;  // C/D: col=lane&15, row=quad*4+reg
      g_D[(rowb + q) * N + m] = nm - 2.f * acc[s][r];
    }
  }
}

// ---------------- top-10: one wave per row ----------------
__global__ __launch_bounds__(256) void topk_kernel(int N) {
  int wid = (blockIdx.x * blockDim.x + threadIdx.x) >> 6;
  int lane = threadIdx.x & 63;
  if (wid >= BNTOT) return;
  int q = wid & (N - 1);
  const float* drow = g_D + (size_t)wid * N;
  float dv[32];
  const int base = lane * 32;
#pragma unroll
  for (int j = 0; j < 32; j += 4) {
    float4 d4 = *(const float4*)(drow + base + j);
    dv[j] = d4.x; dv[j + 1] = d4.y; dv[j + 2] = d4.z; dv[j + 3] = d4.w;
  }
  if (q >= base && q < base + 32) dv[q - base] = FMAX;
  int* ob = g_ws_i + (size_t)wid * 10;
  for (int k = 0; k < 10; ++k) {
    float bd = dv[0]; int bj = 0;
#pragma unroll
    for (int j = 1; j < 32; ++j)
      if (dv[j] < bd) { bd = dv[j]; bj = j; }
    float rd = bd; int rm = base + bj;
#pragma unroll
    for (int off = 32; off > 0; off >>= 1) {
      float od = __shfl_down(rd, off, 64);
      int om = __shfl_down(rm, off, 64);
      if (od < rd || (od == rd && om < rm)) { rd = od; rm = om; }
    }
    rm = __shfl(rm, 0, 64);
    if (lane == 0) ob[k] = rm;
    if (rm >= base && rm < base + 32) dv[rm - base] = FMAX;
  }
}

// ---------------- G[z][BN][64] = X @ W_half[o_base:+64]^T ----------------
template <bool XDYN, int C>
__global__ __launch_bounds__(256) void gmat64_kernel(const void* xraw, size_t xoff,
                                                     int lda, const void* W,
                                                     int o_base, int BN) {
  const int isb = g_flag;
  constexpr int CC = (C <= 4) ? 4 : 64;
  constexpr int NCH = (C + CC - 1) / CC;
  __shared__ __align__(16) float at[CC][68];
  __shared__ __align__(16) float wt[CC][68];
  const int tid = threadIdx.x;
  const int ty = tid >> 4, tx = tid & 15;
  const int r0 = blockIdx.x * 64;
  const int z = blockIdx.z;
  float* Gz = g_ws_f + OFF_G + (size_t)z * BN * 64;
  float acc[4][4];
#pragma unroll
  for (int i = 0; i < 4; ++i)
#pragma unroll
    for (int j = 0; j < 4; ++j) acc[i][j] = 0.f;

  for (int ch = 0; ch < NCH; ++ch) {
    int c0 = ch * CC;
    for (int i = tid; i < 64 * CC; i += 256) {
      int r = i / CC, c = i % CC; int cg = c0 + c;
      size_t gi = (size_t)(r0 + r) * lda + cg;
      at[c][r] = (cg < C) ? (XDYN ? ldany(xraw, gi, isb) : g_ws_f[xoff + gi]) : 0.f;
    }
    for (int i = tid; i < 64 * CC; i += 256) {
      int r = i / CC, c = i % CC; int cg = c0 + c;
      size_t wi = (size_t)(o_base + r) * (2 * C) + (size_t)z * C + cg;
      wt[c][r] = (cg < C) ? ldany(W, wi, isb) : 0.f;
    }
    __syncthreads();
#pragma unroll 8
    for (int c = 0; c < CC; ++c) {
      const float4 a4 = *(const float4*)&at[c][4 * ty];
      const float4 w4 = *(const float4*)&wt[c][4 * tx];
      acc[0][0] += a4.x * w4.x; acc[0][1] += a4.x * w4.y; acc[0][2] += a4.x * w4.z; acc[0][3] += a4.x * w4.w;
      acc[1][0] += a4.y * w4.x; acc[1][1] += a4.y * w4.y; acc[1][2] += a4.y * w4.z; acc[1][3] += a4.y * w4.w;
      acc[2][0] += a4.z * w4.x; acc[2][1] += a4.z * w4.y; acc[2][2] += a4.z * w4.z; acc[2][3] += a4.z * w4.w;
      acc[3][0] += a4.w * w4.x; acc[3][1] += a4.w * w4.y; acc[3][2] += a4.w * w4.z; acc[3][3] += a4.w * w4.w;
    }
    __syncthreads();
  }
#pragma unroll
  for (int i = 0; i < 4; ++i)
#pragma unroll
    for (int j = 0; j < 4; ++j)
      Gz[(size_t)(r0 + 4 * ty + i) * 64 + 4 * tx + j] = acc[i][j];
}

// ---------------- edge-conv epilogue (64-out chunk) ----------------
__global__ void edge_epi64(const void* s, const void* t, int coff,
                           size_t outoff, int BN, int N) {
  const int isb = g_flag;
  int tid = threadIdx.x;
  int p = tid >> 6, o = tid & 63;
  int row = blockIdx.x * 4 + p;
  const float* G1 = g_ws_f + OFF_G;
  const float* G2 = G1 + (size_t)BN * 64;
  float* out = g_ws_f + outoff;
  int b = row / N;
  const int* id = g_ws_i + (size_t)row * 10;
  float g1n = G1[(size_t)row * 64 + o];
  float base = G2[(size_t)row * 64 + o] - g1n;
  float sv = ldany(s, coff + o, isb), tv = ldany(t, coff + o, isb);
  float mx = -FMAX;
#pragma unroll
  for (int k = 0; k < 10; ++k) {
    int m = id[k];
    m = (m < 0) ? 0 : ((m >= N) ? N - 1 : m);
    float h = sv * (G1[((size_t)b * N + m) * 64 + o] + base) + tv;
    h = (h >= 0.f) ? h : NEG * h;
    mx = fmaxf(mx, h);
  }
  out[(size_t)row * 512 + o] = mx;
}

// ---------------- W5 MFMA + max over n (s5>0: scale/bias/lrelu after max) ----
__global__ __launch_bounds__(256) void w5max_mfma(const void* s5, const void* t5, int N) {
  const int tid = threadIdx.x;
  const int wave = tid >> 6, lane = tid & 63;
  const int quad = lane >> 4, l16 = lane & 15;
  const int b = blockIdx.z;
  const int o0 = blockIdx.y * 64, n0 = blockIdx.x * 64;
  f32x4 acc[4];
#pragma unroll
  for (int s = 0; s < 4; ++s) acc[s] = (f32x4){0.f, 0.f, 0.f, 0.f};

  const int arg = (int)(((size_t)b * N + n0) >> 4) + wave;  // A row-group (KT=16)
  const int wrg0 = o0 >> 4;                                 // W5 row-group base
#pragma unroll 4
  for (int kt = 0; kt < 16; ++kt) {
    const size_t abase = ((size_t)arg * 16 + kt) * 512 + lane * 8;
    s8v ah = *(const s8v*)(g_hi + abase);
    s8v al = *(const s8v*)(g_lo + abase);
#pragma unroll
    for (int s = 0; s < 4; ++s) {
      const size_t bbase = ((size_t)(wrg0 + s) * 16 + kt) * 512 + lane * 8;
      s8v bh = *(const s8v*)(g_whi + bbase);
      s8v bl = *(const s8v*)(g_wlo + bbase);
      acc[s] = __builtin_amdgcn_mfma_f32_16x16x32_bf16(ah, bh, acc[s], 0, 0, 0);
      acc[s] = __builtin_amdgcn_mfma_f32_16x16x32_bf16(ah, bl, acc[s], 0, 0, 0);
      acc[s] = __builtin_amdgcn_mfma_f32_16x16x32_bf16(al, bh, acc[s], 0, 0, 0);
    }
  }
  __shared__ float red[4][64];
  const int isb = g_flag;
#pragma unroll
  for (int s = 0; s < 4; ++s) {
    float m4 = fmaxf(fmaxf(acc[s][0], acc[s][1]), fmaxf(acc[s][2], acc[s][3]));
#pragma unroll
    for (int off = 16; off < 64; off <<= 1) m4 = fmaxf(m4, __shfl_down(m4, off, 64));
    if (quad == 0) red[wave][s * 16 + l16] = m4;
  }
  __syncthreads();
  if (tid < 64) {
    float m = fmaxf(fmaxf(red[0][tid], red[1][tid]), fmaxf(red[2][tid], red[3][tid]));
    int o = o0 + tid;
    float sv = ldany(s5, o, isb), tv = ldany(t5, o, isb);
    float h = sv * m + tv;
    h = (h >= 0.f) ? h : NEG * h;
    g_ws_f[OFF_PART + ((size_t)b * 1024 + o) * 32 + blockIdx.x] = h;
  }
}

__global__ void poolred_kernel() {
  const float* part = g_ws_f + OFF_PART;
  float* pooled = g_ws_f + OFF_POOLED;
  int i = blockIdx.x * blockDim.x + threadIdx.x;
  if (i >= 8 * 1024) return;
  const float* p = part + (size_t)i * 32;
  float m = -FMAX;
#pragma unroll
  for (int j = 0; j < 32; ++j) m = fmaxf(m, p[j]);
  pooled[i] = m;
}

// ---------------- FC: one wave per output ----------------
__global__ void fc_kernel(size_t inoff, const void* W, const void* bias,
                          const void* s, const void* t, size_t outoff, int has_out,
                          void* OUTB, int Bb, int IC, int OC, int act) {
  const int isb = g_flag;
  const float* IN = g_ws_f + inoff;
  int gw = (blockIdx.x * blockDim.x + threadIdx.x) >> 6;
  int lane = threadIdx.x & 63;
  if (gw >= Bb * OC) return;
  int b = gw / OC, o = gw % OC;
  const float* in = IN + (size_t)b * IC;
  float acc = 0.f;
  for (int c = lane; c < IC; c += 64) acc += in[c] * ldany(W, (size_t)o * IC + c, isb);
#pragma unroll
  for (int off = 32; off > 0; off >>= 1) acc += __shfl_down(acc, off, 64);
  if (lane == 0) {
    float h = acc;
    if (bias) h += ldany(bias, o, isb);
    if (s) h = h * ldany(s, o, isb) + ldany(t, o, isb);
    if (act) h = (h >= 0.f) ? h : NEG * h;
    if (has_out) g_ws_f[outoff + (size_t)b * OC + o] = h;
    if (OUTB) {
      if (isb) ((bf16*)OUTB)[(size_t)b * OC + o] = __float2bfloat16(h);
      else ((float*)OUTB)[(size_t)b * OC + o] = h;
    }
  }
}

extern "C" void kernel_launch(void* const* d_in, const int* in_sizes, int n_in,
                              void* d_out, int out_size, void* d_ws, size_t ws_size,
                              hipStream_t stream) {
  const int B = 8, N = 2048, BN = B * N;
  const void* points = d_in[0];
  const void *W1 = d_in[1], *s1 = d_in[2], *t1 = d_in[3];
  const void *W2 = d_in[4], *s2 = d_in[5], *t2 = d_in[6];
  const void *W3 = d_in[7], *s3 = d_in[8], *t3 = d_in[9];
  const void *W4 = d_in[10], *s4 = d_in[11], *t4 = d_in[12];
  const void *W5 = d_in[13], *s5 = d_in[14], *t5 = d_in[15];
  const void *Wf1 = d_in[16], *sf1 = d_in[17], *tf1 = d_in[18];
  const void *Wf2 = d_in[19], *bf2 = d_in[20], *sf2 = d_in[21], *tf2 = d_in[22];
  const void *Wf3 = d_in[23], *bf3 = d_in[24];

  probe_kernel<<<1, 1, 0, stream>>>(points);
  // split W5 (1024 rows x CPAD 512, csh2=4) once
  split_kernel<<<(1024 * 512) / 256, 256, 0, stream>>>(W5, 0, 512, 512, 4, 1, 1024 * 512);

  // ---- layer 1: points (C=3, CPAD=32, csh2=0) -> cat[:, 0:64)
  norms_kernel<true><<<BN / 4, 256, 0, stream>>>(points, 0, 3, 3, BN);
  split_kernel<<<(BN * 32) / 256, 256, 0, stream>>>(points, 0, 3, 3, 0, 0, BN * 32);
  dist_mfma<32><<<dim3(N / 64, N / 64, B), 256, 0, stream>>>(N);
  topk_kernel<<<BN / 4, 256, 0, stream>>>(N);
  gmat64_kernel<true, 3><<<dim3(BN / 64, 1, 2), 256, 0, stream>>>(points, 0, 3, W1, 0, BN);
  edge_epi64<<<BN / 4, 256, 0, stream>>>(s1, t1, 0, OFF_CAT + 0, BN, N);
  // ---- layer 2: cat[:,0:64) (C=64, CPAD=64, csh2=1) -> cat[:, 64:128)
  norms_kernel<false><<<BN / 4, 256, 0, stream>>>(nullptr, OFF_CAT + 0, 512, 64, BN);
  split_kernel<<<(BN * 64) / 256, 256, 0, stream>>>(nullptr, OFF_CAT + 0, 512, 64, 1, 0, BN * 64);
  dist_mfma<64><<<dim3(N / 64, N / 64, B), 256, 0, stream>>>(N);
  topk_kernel<<<BN / 4, 256, 0, stream>>>(N);
  gmat64_kernel<false, 64><<<dim3(BN / 64, 1, 2), 256, 0, stream>>>(nullptr, OFF_CAT + 0, 512, W2, 0, BN);
  edge_epi64<<<BN / 4, 256, 0, stream>>>(s2, t2, 0, OFF_CAT + 64, BN, N);
  // ---- layer 3: cat[:,64:128) (C=64) -> cat[:, 128:256)
  norms_kernel<false><<<BN / 4, 256, 0, stream>>>(nullptr, OFF_CAT + 64, 512, 64, BN);
  split_kernel<<<(BN * 64) / 256, 256, 0, stream>>>(nullptr, OFF_CAT + 64, 512, 64, 1, 0, BN * 64);
  dist_mfma<64><<<dim3(N / 64, N / 64, B), 256, 0, stream>>>(N);
  topk_kernel<<<BN / 4, 256, 0, stream>>>(N);
  for (int c = 0; c < 2; ++c) {
    gmat64_kernel<false, 64><<<dim3(BN / 64, 1, 2), 256, 0, stream>>>(nullptr, OFF_CAT + 64, 512, W3, c * 64, BN);
    edge_epi64<<<BN / 4, 256, 0, stream>>>(s3, t3, c * 64, OFF_CAT + 128 + c * 64, BN, N);
  }
  // ---- layer 4: cat[:,128:256) (C=128, CPAD=128, csh2=2) -> cat[:, 256:512)
  norms_kernel<false><<<BN / 4, 256, 0, stream>>>(nullptr, OFF_CAT + 128, 512, 128, BN);
  split_kernel<<<(BN * 128) / 256, 256, 0, stream>>>(nullptr, OFF_CAT + 128, 512, 128, 2, 0, BN * 128);
  dist_mfma<128><<<dim3(N / 64, N / 64, B), 256, 0, stream>>>(N);
  topk_kernel<<<BN / 4, 256, 0, stream>>>(N);
  for (int c = 0; c < 4; ++c) {
    gmat64_kernel<false, 128><<<dim3(BN / 64, 1, 2), 256, 0, stream>>>(nullptr, OFF_CAT + 128, 512, W4, c * 64, BN);
    edge_epi64<<<BN / 4, 256, 0, stream>>>(s4, t4, c * 64, OFF_CAT + 256 + c * 64, BN, N);
  }
  // ---- W5 (split full cat 512 cols, csh2=4) + global max pool
  split_kernel<<<(BN * 512) / 256, 256, 0, stream>>>(nullptr, OFF_CAT, 512, 512, 4, 0, BN * 512);
  w5max_mfma<<<dim3(32, 16, 8), 256, 0, stream>>>(s5, t5, N);
  poolred_kernel<<<32, 256, 0, stream>>>();
  // ---- FC head
  fc_kernel<<<(8 * 512 * 64) / 256, 256, 0, stream>>>(OFF_POOLED, Wf1, nullptr, sf1, tf1, OFF_H1, 1, nullptr, 8, 1024, 512, 1);
  fc_kernel<<<(8 * 256 * 64) / 256, 256, 0, stream>>>(OFF_H1, Wf2, bf2, sf2, tf2, OFF_H2, 1, nullptr, 8, 512, 256, 1);
  fc_kernel<<<6, 256, 0, stream>>>(OFF_H2, Wf3, bf3, nullptr, nullptr, 0, 0, d_out, 8, 256, 3, 0);
}